// Round 7
// baseline (234.024 us; speedup 1.0000x reference)
//
#include <hip/hip_runtime.h>
#include <math.h>

#define NEG_SLOPE 0.2f
#define EPB 8192            // edges per P1 block

typedef __attribute__((ext_vector_type(8))) short bf16x8;
typedef __attribute__((ext_vector_type(4))) float f32x4;

__device__ __forceinline__ unsigned pack_bf16x2(float a, float b) {
    unsigned ua = __float_as_uint(a);
    unsigned ub = __float_as_uint(b);
    ua += 0x7FFFu + ((ua >> 16) & 1u);     // RNE
    ub += 0x7FFFu + ((ub >> 16) & 1u);
    return (ua >> 16) | (ub & 0xFFFF0000u);
}
__device__ __forceinline__ unsigned short bf16r(float f) {
    unsigned u = __float_as_uint(f);
    u += 0x7FFFu + ((u >> 16) & 1u);
    return (unsigned short)(u >> 16);
}
__device__ __forceinline__ float bf_lo(unsigned u) { return __uint_as_float(u << 16); }
__device__ __forceinline__ float bf_hi(unsigned u) { return __uint_as_float(u & 0xFFFF0000u); }

// LDS tile addressing: row stride 256B, XOR swizzle spreads 16 rows over 16B slots
#define SWZ(row, byteoff) ((((row) * 256) + (byteoff)) ^ (((row) & 15) << 4))

// ================= W transpose+bf16 pre-pass: W[k][Nc] f32 -> WT[n][128] bf16 ===========

__global__ __launch_bounds__(256) void wcvt_kernel(const float* __restrict__ W,
                                                   unsigned short* __restrict__ WT,
                                                   int Nc, int total) {
    int id = blockIdx.x * 256 + threadIdx.x;
    if (id < total) {
        int n = id >> 7, k = id & 127;
        WT[id] = bf16r(W[k * Nc + n]);
    }
}

// ================= generic in-place exclusive scan (3 kernels) =================

__global__ __launch_bounds__(256) void gscan_bsum(const int* __restrict__ arr,
                                                  int* __restrict__ psum, int M) {
    __shared__ int red[4];
    int tid = threadIdx.x;
    int idx = blockIdx.x * 256 + tid;
    int v = (idx < M) ? arr[idx] : 0;
    #pragma unroll
    for (int off = 1; off < 64; off <<= 1) v += __shfl_xor(v, off, 64);
    if ((tid & 63) == 0) red[tid >> 6] = v;
    __syncthreads();
    if (tid == 0) psum[blockIdx.x] = red[0] + red[1] + red[2] + red[3];
}

__global__ __launch_bounds__(1024) void gscan_psum(int* __restrict__ psum, int nb) {
    __shared__ int ws[16];
    int tid = threadIdx.x, lane = tid & 63, w = tid >> 6;
    int v = (tid < nb) ? psum[tid] : 0;
    int incl = v;
    #pragma unroll
    for (int off = 1; off < 64; off <<= 1) {
        int t = __shfl_up(incl, off, 64);
        if (lane >= off) incl += t;
    }
    if (lane == 63) ws[w] = incl;
    __syncthreads();
    int wbase = 0;
    #pragma unroll
    for (int j = 0; j < 16; j++) { if (j < w) wbase += ws[j]; }
    if (tid < nb) psum[tid] = wbase + incl - v;   // exclusive
}

__global__ __launch_bounds__(256) void gscan_final(int* __restrict__ arr,
                                                   const int* __restrict__ psum, int M) {
    __shared__ int ws[4];
    int tid = threadIdx.x, lane = tid & 63, w = tid >> 6;
    int idx = blockIdx.x * 256 + tid;
    int v = (idx < M) ? arr[idx] : 0;
    int incl = v;
    #pragma unroll
    for (int off = 1; off < 64; off <<= 1) {
        int t = __shfl_up(incl, off, 64);
        if (lane >= off) incl += t;
    }
    if (lane == 63) ws[w] = incl;
    __syncthreads();
    int wbase = 0;
    #pragma unroll
    for (int j = 0; j < 4; j++) { if (j < w) wbase += ws[j]; }
    if (idx < M) arr[idx] = psum[blockIdx.x] + wbase + incl - v;
}

// ================= CSR build: two-level counting sort, LDS atomics only =================

__global__ __launch_bounds__(256) void p1_hist(const int* __restrict__ dst, int E, int N,
                                               int nblk1, int nbuckets,
                                               int* __restrict__ partial) {
    __shared__ int hist[1024];
    int tid = threadIdx.x;
    for (int i = tid; i < nbuckets; i += 256) hist[i] = 0;
    __syncthreads();
    int base = blockIdx.x * EPB;
    int tot = E + N;
    #pragma unroll
    for (int it = 0; it < EPB / 256; it++) {
        int i = base + it * 256 + tid;
        if (i < tot) {
            int d = (i < E) ? dst[i] : (i - E);   // self-loops appended
            atomicAdd(&hist[d >> 8], 1);          // LDS atomic
        }
    }
    __syncthreads();
    for (int b = tid; b < nbuckets; b += 256)
        partial[b * nblk1 + blockIdx.x] = hist[b];   // bucket-major
}

__global__ __launch_bounds__(256) void p1_scatter(const int* __restrict__ src,
                                                  const int* __restrict__ dst, int E, int N,
                                                  int nblk1, int nbuckets,
                                                  const int* __restrict__ scanned,
                                                  unsigned* __restrict__ pairs) {
    __shared__ int cursor[1024];
    int tid = threadIdx.x;
    for (int b = tid; b < nbuckets; b += 256)
        cursor[b] = scanned[b * nblk1 + blockIdx.x];
    __syncthreads();
    int base = blockIdx.x * EPB;
    int tot = E + N;
    #pragma unroll
    for (int it = 0; it < EPB / 256; it++) {
        int i = base + it * 256 + tid;
        if (i < tot) {
            int s = (i < E) ? src[i] : (i - E);
            int d = (i < E) ? dst[i] : (i - E);
            int pos = atomicAdd(&cursor[d >> 8], 1);  // LDS atomic w/ return
            pairs[pos] = ((unsigned)(d & 255) << 24) | (unsigned)s;
        }
    }
}

#define P2CAP 8192

// p2: finish counting sort AND compute per-edge layer-1 attention numerators
// exa[pos] = exp(leakyrelu(as1[src] + ad1[dst])) per head (float4).
__global__ __launch_bounds__(256) void p2_kernel(const unsigned* __restrict__ pairs,
                                                 const int* __restrict__ scanned,
                                                 int nblk1, int nbuckets, int Etot, int N,
                                                 const float4* __restrict__ as4,
                                                 const float4* __restrict__ ad4,
                                                 int* __restrict__ rowptr,
                                                 int* __restrict__ col,
                                                 float4* __restrict__ exa) {
    __shared__ unsigned buf[P2CAP];     // 32 KB: bucket staged once from global
    __shared__ int cnt[256];
    __shared__ int cur[256];
    __shared__ int wsum[4];
    int b = blockIdx.x;
    int tid = threadIdx.x, lane = tid & 63, w = tid >> 6;
    int bucketStart = scanned[b * nblk1];
    int bucketEnd = (b + 1 < nbuckets) ? scanned[(b + 1) * nblk1] : Etot;
    int sz = bucketEnd - bucketStart;
    bool inLds = (sz <= P2CAP);
    cnt[tid] = 0;
    if (inLds) {
        for (int i = tid; i < sz; i += 256) buf[i] = pairs[bucketStart + i];
    }
    __syncthreads();
    if (inLds) {
        for (int i = tid; i < sz; i += 256) atomicAdd(&cnt[buf[i] >> 24], 1);
    } else {
        for (int i = bucketStart + tid; i < bucketEnd; i += 256)
            atomicAdd(&cnt[pairs[i] >> 24], 1);
    }
    __syncthreads();
    int v = cnt[tid];
    int incl = v;
    #pragma unroll
    for (int off = 1; off < 64; off <<= 1) {
        int t = __shfl_up(incl, off, 64);
        if (lane >= off) incl += t;
    }
    if (lane == 63) wsum[w] = incl;
    __syncthreads();
    int wbase = 0;
    #pragma unroll
    for (int j = 0; j < 4; j++) { if (j < w) wbase += wsum[j]; }
    int base = bucketStart + wbase + incl - v;   // exclusive position for this local dst
    cur[tid] = base;
    int d = b * 256 + tid;
    if (d < N) rowptr[d] = base;
    if (b == nbuckets - 1 && tid == 0) rowptr[N] = Etot;
    __syncthreads();
    if (inLds) {
        for (int i = tid; i < sz; i += 256) {
            unsigned p = buf[i];
            int dl = p >> 24, s = (int)(p & 0xFFFFFFu);
            int pos = atomicAdd(&cur[dl], 1);
            col[pos] = s;
            float4 A = as4[s];
            float4 D = ad4[b * 256 + dl];
            float4 ex;
            float e;
            e = A.x + D.x; e = fmaxf(e, e * NEG_SLOPE); ex.x = __expf(e);
            e = A.y + D.y; e = fmaxf(e, e * NEG_SLOPE); ex.y = __expf(e);
            e = A.z + D.z; e = fmaxf(e, e * NEG_SLOPE); ex.z = __expf(e);
            e = A.w + D.w; e = fmaxf(e, e * NEG_SLOPE); ex.w = __expf(e);
            exa[pos] = ex;
        }
    } else {
        for (int i = bucketStart + tid; i < bucketEnd; i += 256) {
            unsigned p = pairs[i];
            int dl = p >> 24, s = (int)(p & 0xFFFFFFu);
            int pos = atomicAdd(&cur[dl], 1);
            col[pos] = s;
            float4 A = as4[s];
            float4 D = ad4[b * 256 + dl];
            float4 ex;
            float e;
            e = A.x + D.x; e = fmaxf(e, e * NEG_SLOPE); ex.x = __expf(e);
            e = A.y + D.y; e = fmaxf(e, e * NEG_SLOPE); ex.y = __expf(e);
            e = A.z + D.z; e = fmaxf(e, e * NEG_SLOPE); ex.z = __expf(e);
            e = A.w + D.w; e = fmaxf(e, e * NEG_SLOPE); ex.w = __expf(e);
            exa[pos] = ex;
        }
    }
}

// ================= Layer 1 GEMM (MFMA bf16): h1 = x @ W1, plus as1/ad1 =================

__global__ __launch_bounds__(256) void gemm1_kernel(const float* __restrict__ x,
                                                    const unsigned short* __restrict__ W1T,
                                                    const float* __restrict__ a_s,
                                                    const float* __restrict__ a_d,
                                                    uint4* __restrict__ h1b,
                                                    float* __restrict__ as1,
                                                    float* __restrict__ ad1, int N) {
    __shared__ char xs[16384];          // A tile / later h1 tile (bf16, swizzled)
    __shared__ char wsm[32768];         // B tile = W1T (bf16, swizzled)
    int tid = threadIdx.x;
    int row0 = blockIdx.x * 64;

    #pragma unroll
    for (int it = 0; it < 8; it++) {
        int idx = it * 256 + tid;
        int n = idx >> 4, kq = idx & 15;
        uint4 v = ((const uint4*)W1T)[idx];
        *(uint4*)(wsm + SWZ(n, kq * 16)) = v;
    }
    #pragma unroll
    for (int it = 0; it < 8; it++) {
        int idx = it * 256 + tid;
        int r = idx >> 5, k4 = idx & 31;
        int row = row0 + r;
        float4 v = (row < N) ? ((const float4*)x)[(size_t)row * 32 + k4]
                             : make_float4(0.f, 0.f, 0.f, 0.f);
        uint2 p;
        p.x = pack_bf16x2(v.x, v.y);
        p.y = pack_bf16x2(v.z, v.w);
        *(uint2*)(xs + SWZ(r, k4 * 8)) = p;
    }
    __syncthreads();

    int wv = tid >> 6, lane = tid & 63;
    int r0 = wv * 16;
    int lm = lane & 15, lk = lane >> 4;

    bf16x8 afr[4];
    #pragma unroll
    for (int ks = 0; ks < 4; ks++) {
        int row = r0 + lm;
        afr[ks] = *(const bf16x8*)(xs + SWZ(row, ks * 64 + lk * 16));
    }
    f32x4 acc[8];
    #pragma unroll
    for (int nt = 0; nt < 8; nt++) acc[nt] = (f32x4){0.f, 0.f, 0.f, 0.f};

    #pragma unroll
    for (int nt = 0; nt < 8; nt++) {
        int c = nt * 16 + lm;
        #pragma unroll
        for (int ks = 0; ks < 4; ks++) {
            bf16x8 bfr = *(const bf16x8*)(wsm + SWZ(c, ks * 64 + lk * 16));
            acc[nt] = __builtin_amdgcn_mfma_f32_16x16x32_bf16(afr[ks], bfr, acc[nt], 0, 0, 0);
        }
    }
    __syncthreads();   // all waves done reading xs -> reuse as output tile

    #pragma unroll
    for (int nt = 0; nt < 8; nt++) {
        int c = nt * 16 + lm;
        #pragma unroll
        for (int e = 0; e < 4; e++) {
            int row = r0 + lk * 4 + e;
            *(unsigned short*)(xs + SWZ(row, c * 2)) = bf16r(acc[nt][e]);
        }
    }
    __syncthreads();

    #pragma unroll
    for (int it = 0; it < 4; it++) {
        int idx = it * 256 + tid;
        int row = idx >> 4, q = idx & 15;
        if (row0 + row < N) {
            uint4 v = *(const uint4*)(xs + SWZ(row, q * 16));
            h1b[(size_t)(row0 + row) * 16 + q] = v;
        }
    }
    {
        int row = tid >> 2, h = tid & 3;
        if (row0 + row < N) {
            float sd = 0.f, dd = 0.f;
            #pragma unroll
            for (int q = 0; q < 4; q++) {
                uint4 v = *(const uint4*)(xs + SWZ(row, h * 64 + q * 16));
                unsigned uu[4] = {v.x, v.y, v.z, v.w};
                #pragma unroll
                for (int j = 0; j < 4; j++) {
                    int k = h * 32 + q * 8 + 2 * j;
                    sd = fmaf(bf_lo(uu[j]), a_s[k], sd);
                    sd = fmaf(bf_hi(uu[j]), a_s[k + 1], sd);
                    dd = fmaf(bf_lo(uu[j]), a_d[k], dd);
                    dd = fmaf(bf_hi(uu[j]), a_d[k + 1], dd);
                }
            }
            as1[(row0 + row) * 4 + h] = sd;
            ad1[(row0 + row) * 4 + h] = dd;
        }
    }
}

// ---------------- Layer 1 aggregation: precomputed exp, bf16 gather, 16 in flight -------

__global__ __launch_bounds__(256) void agg1_kernel(const int* __restrict__ rowptr,
                                                   const int* __restrict__ col,
                                                   const unsigned* __restrict__ h1b,
                                                   const float* __restrict__ exa,
                                                   const float* __restrict__ b1,
                                                   unsigned* __restrict__ out1b, int N) {
    int lane = threadIdx.x & 63;
    int wid = __builtin_amdgcn_readfirstlane(threadIdx.x >> 6);
    int n = blockIdx.x * 4 + wid;
    if (n >= N) return;
    int hh = lane >> 4;                  // head of channels 2*lane, 2*lane+1
    int beg = rowptr[n], end = rowptr[n + 1];
    float ax0 = 0.f, ay0 = 0.f, den0 = 0.f;
    float ax1 = 0.f, ay1 = 0.f, den1 = 0.f;
    int i = beg;
    for (; i + 16 <= end; i += 16) {
        int ss[16];
        float ex[16];
        unsigned uu[16];
        #pragma unroll
        for (int j = 0; j < 16; j++) ss[j] = col[i + j];
        #pragma unroll
        for (int j = 0; j < 16; j++) {
            ex[j] = exa[(i + j) * 4 + hh];
            uu[j] = h1b[ss[j] * 64 + lane];
        }
        #pragma unroll
        for (int j = 0; j < 16; j++) {
            if (j & 1) {
                den1 += ex[j];
                ax1 = fmaf(ex[j], bf_lo(uu[j]), ax1);
                ay1 = fmaf(ex[j], bf_hi(uu[j]), ay1);
            } else {
                den0 += ex[j];
                ax0 = fmaf(ex[j], bf_lo(uu[j]), ax0);
                ay0 = fmaf(ex[j], bf_hi(uu[j]), ay0);
            }
        }
    }
    for (; i + 4 <= end; i += 4) {
        int ss[4];
        float ex[4];
        unsigned uu[4];
        #pragma unroll
        for (int j = 0; j < 4; j++) ss[j] = col[i + j];
        #pragma unroll
        for (int j = 0; j < 4; j++) {
            ex[j] = exa[(i + j) * 4 + hh];
            uu[j] = h1b[ss[j] * 64 + lane];
        }
        #pragma unroll
        for (int j = 0; j < 4; j++) {
            den0 += ex[j];
            ax0 = fmaf(ex[j], bf_lo(uu[j]), ax0);
            ay0 = fmaf(ex[j], bf_hi(uu[j]), ay0);
        }
    }
    for (; i < end; i++) {
        int s = col[i];
        float ex = exa[i * 4 + hh];
        unsigned u = h1b[s * 64 + lane];
        den0 += ex;
        ax0 = fmaf(ex, bf_lo(u), ax0);
        ay0 = fmaf(ex, bf_hi(u), ay0);
    }
    float den = den0 + den1, ax = ax0 + ax1, ay = ay0 + ay1;
    float2 bb = ((const float2*)b1)[lane];
    float ox = fmaxf(ax / den + bb.x, 0.f);
    float oy = fmaxf(ay / den + bb.y, 0.f);
    out1b[n * 64 + lane] = pack_bf16x2(ox, oy);
}

// ================= Layer 2 GEMM (MFMA bf16): h2 = relu_h @ W2, plus as2/ad2 =============

__global__ __launch_bounds__(256) void gemm2_kernel(const uint4* __restrict__ out1b,
                                                    const unsigned short* __restrict__ W2T,
                                                    const float* __restrict__ a_s,
                                                    const float* __restrict__ a_d,
                                                    uint4* __restrict__ h2b,
                                                    float* __restrict__ as2,
                                                    float* __restrict__ ad2, int N) {
    __shared__ char xs[16384];          // A tile / later h2 tile
    __shared__ char wsm[8192];          // W2T 32x128 bf16
    int tid = threadIdx.x;
    int row0 = blockIdx.x * 64;

    #pragma unroll
    for (int it = 0; it < 2; it++) {
        int idx = it * 256 + tid;
        int n = idx >> 4, kq = idx & 15;
        uint4 v = ((const uint4*)W2T)[idx];
        *(uint4*)(wsm + SWZ(n, kq * 16)) = v;
    }
    #pragma unroll
    for (int it = 0; it < 4; it++) {
        int idx = it * 256 + tid;
        int r = idx >> 4, q = idx & 15;
        int row = row0 + r;
        uint4 v = (row < N) ? out1b[(size_t)row * 16 + q] : make_uint4(0, 0, 0, 0);
        *(uint4*)(xs + SWZ(r, q * 16)) = v;
    }
    __syncthreads();

    int wv = tid >> 6, lane = tid & 63;
    int r0 = wv * 16;
    int lm = lane & 15, lk = lane >> 4;

    bf16x8 afr[4];
    #pragma unroll
    for (int ks = 0; ks < 4; ks++) {
        int row = r0 + lm;
        afr[ks] = *(const bf16x8*)(xs + SWZ(row, ks * 64 + lk * 16));
    }
    f32x4 acc[2];
    acc[0] = (f32x4){0.f, 0.f, 0.f, 0.f};
    acc[1] = (f32x4){0.f, 0.f, 0.f, 0.f};
    #pragma unroll
    for (int nt = 0; nt < 2; nt++) {
        int c = nt * 16 + lm;
        #pragma unroll
        for (int ks = 0; ks < 4; ks++) {
            bf16x8 bfr = *(const bf16x8*)(wsm + SWZ(c, ks * 64 + lk * 16));
            acc[nt] = __builtin_amdgcn_mfma_f32_16x16x32_bf16(afr[ks], bfr, acc[nt], 0, 0, 0);
        }
    }
    __syncthreads();

    #pragma unroll
    for (int nt = 0; nt < 2; nt++) {
        int c = nt * 16 + lm;
        #pragma unroll
        for (int e = 0; e < 4; e++) {
            int row = r0 + lk * 4 + e;
            *(unsigned short*)(xs + SWZ(row, c * 2)) = bf16r(acc[nt][e]);
        }
    }
    __syncthreads();

    {
        int row = tid >> 2, q = tid & 3;
        if (row0 + row < N) {
            uint4 v = *(const uint4*)(xs + SWZ(row, q * 16));
            h2b[(size_t)(row0 + row) * 4 + q] = v;
        }
    }
    if (tid < 64 && row0 + tid < N) {
        float sd = 0.f, dd = 0.f;
        #pragma unroll
        for (int q = 0; q < 4; q++) {
            uint4 v = *(const uint4*)(xs + SWZ(tid, q * 16));
            unsigned uu[4] = {v.x, v.y, v.z, v.w};
            #pragma unroll
            for (int j = 0; j < 4; j++) {
                int k = q * 8 + 2 * j;
                sd = fmaf(bf_lo(uu[j]), a_s[k], sd);
                sd = fmaf(bf_hi(uu[j]), a_s[k + 1], sd);
                dd = fmaf(bf_lo(uu[j]), a_d[k], dd);
                dd = fmaf(bf_hi(uu[j]), a_d[k + 1], dd);
            }
        }
        as2[row0 + tid] = sd;
        ad2[row0 + tid] = dd;
    }
}

// ---------------- Layer 2 aggregation: 16 edges/wave in flight ----------------

#define AGG2_EDGE(u, l)                                            \
    {                                                              \
        float e = l + adn;                                         \
        e = fmaxf(e, e * NEG_SLOPE);                               \
        float ex = __expf(e);                                      \
        den += ex;                                                 \
        a0 = fmaf(ex, bf_lo(u), a0);                               \
        a1 = fmaf(ex, bf_hi(u), a1);                               \
    }

__global__ __launch_bounds__(256) void agg2_kernel(const int* __restrict__ rowptr,
                                                   const int* __restrict__ col,
                                                   const unsigned* __restrict__ h2b,
                                                   const float* __restrict__ as2,
                                                   const float* __restrict__ ad2,
                                                   const float* __restrict__ b2,
                                                   float* __restrict__ out, int N) {
    int lane = threadIdx.x & 63;
    int wid = __builtin_amdgcn_readfirstlane(threadIdx.x >> 6);
    int n = blockIdx.x * 4 + wid;
    if (n >= N) return;
    int q = lane >> 4, c2 = lane & 15;
    float adn = ad2[n];
    int beg = rowptr[n], end = rowptr[n + 1];
    float a0 = 0.f, a1 = 0.f, den = 0.f;
    int i = beg;
    for (; i + 16 <= end; i += 16) {
        int s0 = col[i + q];
        int s1 = col[i + 4 + q];
        int s2 = col[i + 8 + q];
        int s3 = col[i + 12 + q];
        unsigned u0 = h2b[s0 * 16 + c2];
        unsigned u1 = h2b[s1 * 16 + c2];
        unsigned u2 = h2b[s2 * 16 + c2];
        unsigned u3 = h2b[s3 * 16 + c2];
        float l0 = as2[s0], l1 = as2[s1], l2 = as2[s2], l3 = as2[s3];
        AGG2_EDGE(u0, l0) AGG2_EDGE(u1, l1) AGG2_EDGE(u2, l2) AGG2_EDGE(u3, l3)
    }
    for (; i + 4 <= end; i += 4) {
        int s = col[i + q];
        unsigned u = h2b[s * 16 + c2];
        float l = as2[s];
        AGG2_EDGE(u, l)
    }
    if (i + q < end) {
        int s = col[i + q];
        unsigned u = h2b[s * 16 + c2];
        float l = as2[s];
        AGG2_EDGE(u, l)
    }
    den += __shfl_xor(den, 16, 64);
    den += __shfl_xor(den, 32, 64);
    a0 += __shfl_xor(a0, 16, 64);
    a0 += __shfl_xor(a0, 32, 64);
    a1 += __shfl_xor(a1, 16, 64);
    a1 += __shfl_xor(a1, 32, 64);
    if (q == 0) {
        float2 bb = ((const float2*)b2)[c2];
        ((float2*)out)[n * 16 + c2] = make_float2(a0 / den + bb.x, a1 / den + bb.y);
    }
}

// ---------------- launch ----------------

extern "C" void kernel_launch(void* const* d_in, const int* in_sizes, int n_in,
                              void* d_out, int out_size, void* d_ws, size_t ws_size,
                              hipStream_t stream) {
    const float* x    = (const float*)d_in[0];
    const int*   ei   = (const int*)d_in[1];
    const float* W1   = (const float*)d_in[2];
    const float* a_s1 = (const float*)d_in[3];
    const float* a_d1 = (const float*)d_in[4];
    const float* b1   = (const float*)d_in[5];
    const float* W2   = (const float*)d_in[6];
    const float* a_s2 = (const float*)d_in[7];
    const float* a_d2 = (const float*)d_in[8];
    const float* b2   = (const float*)d_in[9];

    int N = in_sizes[0] / 128;
    int E = in_sizes[1] / 2;
    const int* srcA = ei;
    const int* dstA = ei + E;
    int Etot = E + N;

    char* ws = (char*)d_ws;
    size_t off = 0;
    auto alloc = [&](size_t bytes) {
        void* p = ws + off;
        off += (bytes + 255) & ~(size_t)255;
        return p;
    };
    unsigned* h1b   = (unsigned*)alloc((size_t)N * 128 * 2);
    unsigned* out1b = (unsigned*)alloc((size_t)N * 128 * 2);
    unsigned* h2b   = (unsigned*)alloc((size_t)N * 32 * 2);
    float* as1      = (float*)alloc((size_t)N * 4 * 4);
    float* ad1      = (float*)alloc((size_t)N * 4 * 4);
    float* as2      = (float*)alloc((size_t)N * 4);
    float* ad2      = (float*)alloc((size_t)N * 4);
    int*   rowptr   = (int*)alloc((size_t)(N + 1) * 4);
    int*   col      = (int*)alloc((size_t)Etot * 4);
    unsigned* pairs = (unsigned*)alloc((size_t)Etot * 4);
    float* exa      = (float*)alloc((size_t)Etot * 16);
    unsigned short* W1T = (unsigned short*)alloc(128 * 128 * 2);
    unsigned short* W2T = (unsigned short*)alloc(32 * 128 * 2);

    int nbuckets = (N + 255) >> 8;                 // 391
    int nblk1 = (Etot + EPB - 1) / EPB;            // 208
    int M = nbuckets * nblk1;
    int*   partial = (int*)alloc((size_t)M * 4);
    int nbs = (M + 255) / 256;
    int*   psum    = (int*)alloc((size_t)1024 * 4);

    // weight transpose/convert + layer-1 GEMM (as1/ad1 needed by p2)
    hipLaunchKernelGGL(wcvt_kernel, dim3(64), dim3(256), 0, stream, W1, W1T, 128, 16384);
    hipLaunchKernelGGL(wcvt_kernel, dim3(16), dim3(256), 0, stream, W2, W2T, 32, 4096);
    hipLaunchKernelGGL(gemm1_kernel, dim3((N + 63) / 64), dim3(256), 0, stream,
                       x, W1T, a_s1, a_d1, (uint4*)h1b, as1, ad1, N);

    // CSR build (LDS-atomic two-level counting sort), p2 fused with exp precompute
    hipLaunchKernelGGL(p1_hist, dim3(nblk1), dim3(256), 0, stream,
                       dstA, E, N, nblk1, nbuckets, partial);
    hipLaunchKernelGGL(gscan_bsum, dim3(nbs), dim3(256), 0, stream, partial, psum, M);
    hipLaunchKernelGGL(gscan_psum, dim3(1), dim3(1024), 0, stream, psum, nbs);
    hipLaunchKernelGGL(gscan_final, dim3(nbs), dim3(256), 0, stream, partial, psum, M);
    hipLaunchKernelGGL(p1_scatter, dim3(nblk1), dim3(256), 0, stream,
                       srcA, dstA, E, N, nblk1, nbuckets, partial, pairs);
    hipLaunchKernelGGL(p2_kernel, dim3(nbuckets), dim3(256), 0, stream,
                       pairs, partial, nblk1, nbuckets, Etot, N,
                       (const float4*)as1, (const float4*)ad1, rowptr, col, (float4*)exa);

    // GAT layers
    hipLaunchKernelGGL(agg1_kernel, dim3((N + 3) / 4), dim3(256), 0, stream,
                       rowptr, col, h1b, exa, b1, out1b, N);
    hipLaunchKernelGGL(gemm2_kernel, dim3((N + 63) / 64), dim3(256), 0, stream,
                       (const uint4*)out1b, W2T, a_s2, a_d2, (uint4*)h2b, as2, ad2, N);
    hipLaunchKernelGGL(agg2_kernel, dim3((N + 3) / 4), dim3(256), 0, stream,
                       rowptr, col, h2b, as2, ad2, b2, (float*)d_out, N);
}

// Round 8
// 231.508 us; speedup vs baseline: 1.0109x; 1.0109x over previous
//
#include <hip/hip_runtime.h>
#include <math.h>

#define NEG_SLOPE 0.2f
#define EPB 8192            // edges per P1 block

typedef __attribute__((ext_vector_type(8))) short bf16x8;
typedef __attribute__((ext_vector_type(4))) float f32x4;

__device__ __forceinline__ unsigned pack_bf16x2(float a, float b) {
    unsigned ua = __float_as_uint(a);
    unsigned ub = __float_as_uint(b);
    ua += 0x7FFFu + ((ua >> 16) & 1u);     // RNE
    ub += 0x7FFFu + ((ub >> 16) & 1u);
    return (ua >> 16) | (ub & 0xFFFF0000u);
}
__device__ __forceinline__ unsigned short bf16r(float f) {
    unsigned u = __float_as_uint(f);
    u += 0x7FFFu + ((u >> 16) & 1u);
    return (unsigned short)(u >> 16);
}
__device__ __forceinline__ float bf_lo(unsigned u) { return __uint_as_float(u << 16); }
__device__ __forceinline__ float bf_hi(unsigned u) { return __uint_as_float(u & 0xFFFF0000u); }

// LDS tile addressing: row stride 256B, XOR swizzle spreads 16 rows over 16B slots
#define SWZ(row, byteoff) ((((row) * 256) + (byteoff)) ^ (((row) & 15) << 4))

// ================= W transpose+bf16 pre-pass: W[k][Nc] f32 -> WT[n][128] bf16 ===========

__global__ __launch_bounds__(256) void wcvt_kernel(const float* __restrict__ W,
                                                   unsigned short* __restrict__ WT,
                                                   int Nc, int total) {
    int id = blockIdx.x * 256 + threadIdx.x;
    if (id < total) {
        int n = id >> 7, k = id & 127;
        WT[id] = bf16r(W[k * Nc + n]);
    }
}

// ================= generic in-place exclusive scan (3 kernels) =================

__global__ __launch_bounds__(256) void gscan_bsum(const int* __restrict__ arr,
                                                  int* __restrict__ psum, int M) {
    __shared__ int red[4];
    int tid = threadIdx.x;
    int idx = blockIdx.x * 256 + tid;
    int v = (idx < M) ? arr[idx] : 0;
    #pragma unroll
    for (int off = 1; off < 64; off <<= 1) v += __shfl_xor(v, off, 64);
    if ((tid & 63) == 0) red[tid >> 6] = v;
    __syncthreads();
    if (tid == 0) psum[blockIdx.x] = red[0] + red[1] + red[2] + red[3];
}

__global__ __launch_bounds__(1024) void gscan_psum(int* __restrict__ psum, int nb) {
    __shared__ int ws[16];
    int tid = threadIdx.x, lane = tid & 63, w = tid >> 6;
    int v = (tid < nb) ? psum[tid] : 0;
    int incl = v;
    #pragma unroll
    for (int off = 1; off < 64; off <<= 1) {
        int t = __shfl_up(incl, off, 64);
        if (lane >= off) incl += t;
    }
    if (lane == 63) ws[w] = incl;
    __syncthreads();
    int wbase = 0;
    #pragma unroll
    for (int j = 0; j < 16; j++) { if (j < w) wbase += ws[j]; }
    if (tid < nb) psum[tid] = wbase + incl - v;   // exclusive
}

__global__ __launch_bounds__(256) void gscan_final(int* __restrict__ arr,
                                                   const int* __restrict__ psum, int M) {
    __shared__ int ws[4];
    int tid = threadIdx.x, lane = tid & 63, w = tid >> 6;
    int idx = blockIdx.x * 256 + tid;
    int v = (idx < M) ? arr[idx] : 0;
    int incl = v;
    #pragma unroll
    for (int off = 1; off < 64; off <<= 1) {
        int t = __shfl_up(incl, off, 64);
        if (lane >= off) incl += t;
    }
    if (lane == 63) ws[w] = incl;
    __syncthreads();
    int wbase = 0;
    #pragma unroll
    for (int j = 0; j < 4; j++) { if (j < w) wbase += ws[j]; }
    if (idx < M) arr[idx] = psum[blockIdx.x] + wbase + incl - v;
}

// ================= CSR build: two-level counting sort, LDS atomics only =================

__global__ __launch_bounds__(256) void p1_hist(const int* __restrict__ dst, int E, int N,
                                               int nblk1, int nbuckets,
                                               int* __restrict__ partial) {
    __shared__ int hist[1024];
    int tid = threadIdx.x;
    for (int i = tid; i < nbuckets; i += 256) hist[i] = 0;
    __syncthreads();
    int base = blockIdx.x * EPB;
    int tot = E + N;
    #pragma unroll
    for (int it = 0; it < EPB / 256; it++) {
        int i = base + it * 256 + tid;
        if (i < tot) {
            int d = (i < E) ? dst[i] : (i - E);   // self-loops appended
            atomicAdd(&hist[d >> 8], 1);          // LDS atomic
        }
    }
    __syncthreads();
    for (int b = tid; b < nbuckets; b += 256)
        partial[b * nblk1 + blockIdx.x] = hist[b];   // bucket-major
}

__global__ __launch_bounds__(256) void p1_scatter(const int* __restrict__ src,
                                                  const int* __restrict__ dst, int E, int N,
                                                  int nblk1, int nbuckets,
                                                  const int* __restrict__ scanned,
                                                  unsigned* __restrict__ pairs) {
    __shared__ int cursor[1024];
    int tid = threadIdx.x;
    for (int b = tid; b < nbuckets; b += 256)
        cursor[b] = scanned[b * nblk1 + blockIdx.x];
    __syncthreads();
    int base = blockIdx.x * EPB;
    int tot = E + N;
    #pragma unroll
    for (int it = 0; it < EPB / 256; it++) {
        int i = base + it * 256 + tid;
        if (i < tot) {
            int s = (i < E) ? src[i] : (i - E);
            int d = (i < E) ? dst[i] : (i - E);
            int pos = atomicAdd(&cursor[d >> 8], 1);  // LDS atomic w/ return
            pairs[pos] = ((unsigned)(d & 255) << 24) | (unsigned)s;
        }
    }
}

#define P2CAP 8192

__global__ __launch_bounds__(256) void p2_kernel(const unsigned* __restrict__ pairs,
                                                 const int* __restrict__ scanned,
                                                 int nblk1, int nbuckets, int Etot, int N,
                                                 int* __restrict__ rowptr,
                                                 int* __restrict__ col,
                                                 int* __restrict__ edst) {
    __shared__ unsigned buf[P2CAP];     // 32 KB: bucket staged once from global
    __shared__ int cnt[256];
    __shared__ int cur[256];
    __shared__ int wsum[4];
    int b = blockIdx.x;
    int tid = threadIdx.x, lane = tid & 63, w = tid >> 6;
    int bucketStart = scanned[b * nblk1];
    int bucketEnd = (b + 1 < nbuckets) ? scanned[(b + 1) * nblk1] : Etot;
    int sz = bucketEnd - bucketStart;
    bool inLds = (sz <= P2CAP);
    cnt[tid] = 0;
    if (inLds) {
        for (int i = tid; i < sz; i += 256) buf[i] = pairs[bucketStart + i];
    }
    __syncthreads();
    if (inLds) {
        for (int i = tid; i < sz; i += 256) atomicAdd(&cnt[buf[i] >> 24], 1);
    } else {
        for (int i = bucketStart + tid; i < bucketEnd; i += 256)
            atomicAdd(&cnt[pairs[i] >> 24], 1);
    }
    __syncthreads();
    int v = cnt[tid];
    int incl = v;
    #pragma unroll
    for (int off = 1; off < 64; off <<= 1) {
        int t = __shfl_up(incl, off, 64);
        if (lane >= off) incl += t;
    }
    if (lane == 63) wsum[w] = incl;
    __syncthreads();
    int wbase = 0;
    #pragma unroll
    for (int j = 0; j < 4; j++) { if (j < w) wbase += wsum[j]; }
    int base = bucketStart + wbase + incl - v;   // exclusive position for this local dst
    cur[tid] = base;
    int d = b * 256 + tid;
    if (d < N) rowptr[d] = base;
    if (b == nbuckets - 1 && tid == 0) rowptr[N] = Etot;
    __syncthreads();
    if (inLds) {
        for (int i = tid; i < sz; i += 256) {
            unsigned p = buf[i];
            int dl = p >> 24;
            int pos = atomicAdd(&cur[dl], 1);
            col[pos] = (int)(p & 0xFFFFFFu);
            edst[pos] = b * 256 + dl;
        }
    } else {
        for (int i = bucketStart + tid; i < bucketEnd; i += 256) {
            unsigned p = pairs[i];
            int dl = p >> 24;
            int pos = atomicAdd(&cur[dl], 1);
            col[pos] = (int)(p & 0xFFFFFFu);
            edst[pos] = b * 256 + dl;
        }
    }
}

// ================= exk: per-edge attention numerators, fully parallel ===================
// exa[pos] = exp(leakyrelu(as1[col[pos]] + ad1[edst[pos]])) per head (float4).

__global__ __launch_bounds__(256) void exk_kernel(const int* __restrict__ col,
                                                  const int* __restrict__ edst,
                                                  const float4* __restrict__ as4,
                                                  const float4* __restrict__ ad4,
                                                  float4* __restrict__ exa, int Etot) {
    int i = blockIdx.x * 256 + threadIdx.x;
    if (i < Etot) {
        int s = col[i], d = edst[i];
        float4 A = as4[s];
        float4 D = ad4[d];
        float4 ex;
        float e;
        e = A.x + D.x; e = fmaxf(e, e * NEG_SLOPE); ex.x = __expf(e);
        e = A.y + D.y; e = fmaxf(e, e * NEG_SLOPE); ex.y = __expf(e);
        e = A.z + D.z; e = fmaxf(e, e * NEG_SLOPE); ex.z = __expf(e);
        e = A.w + D.w; e = fmaxf(e, e * NEG_SLOPE); ex.w = __expf(e);
        exa[i] = ex;
    }
}

// ================= Layer 1 GEMM (MFMA bf16): h1 = x @ W1, plus as1/ad1 =================

__global__ __launch_bounds__(256) void gemm1_kernel(const float* __restrict__ x,
                                                    const unsigned short* __restrict__ W1T,
                                                    const float* __restrict__ a_s,
                                                    const float* __restrict__ a_d,
                                                    uint4* __restrict__ h1b,
                                                    float* __restrict__ as1,
                                                    float* __restrict__ ad1, int N) {
    __shared__ char xs[16384];          // A tile / later h1 tile (bf16, swizzled)
    __shared__ char wsm[32768];         // B tile = W1T (bf16, swizzled)
    int tid = threadIdx.x;
    int row0 = blockIdx.x * 64;

    #pragma unroll
    for (int it = 0; it < 8; it++) {
        int idx = it * 256 + tid;
        int n = idx >> 4, kq = idx & 15;
        uint4 v = ((const uint4*)W1T)[idx];
        *(uint4*)(wsm + SWZ(n, kq * 16)) = v;
    }
    #pragma unroll
    for (int it = 0; it < 8; it++) {
        int idx = it * 256 + tid;
        int r = idx >> 5, k4 = idx & 31;
        int row = row0 + r;
        float4 v = (row < N) ? ((const float4*)x)[(size_t)row * 32 + k4]
                             : make_float4(0.f, 0.f, 0.f, 0.f);
        uint2 p;
        p.x = pack_bf16x2(v.x, v.y);
        p.y = pack_bf16x2(v.z, v.w);
        *(uint2*)(xs + SWZ(r, k4 * 8)) = p;
    }
    __syncthreads();

    int wv = tid >> 6, lane = tid & 63;
    int r0 = wv * 16;
    int lm = lane & 15, lk = lane >> 4;

    bf16x8 afr[4];
    #pragma unroll
    for (int ks = 0; ks < 4; ks++) {
        int row = r0 + lm;
        afr[ks] = *(const bf16x8*)(xs + SWZ(row, ks * 64 + lk * 16));
    }
    f32x4 acc[8];
    #pragma unroll
    for (int nt = 0; nt < 8; nt++) acc[nt] = (f32x4){0.f, 0.f, 0.f, 0.f};

    #pragma unroll
    for (int nt = 0; nt < 8; nt++) {
        int c = nt * 16 + lm;
        #pragma unroll
        for (int ks = 0; ks < 4; ks++) {
            bf16x8 bfr = *(const bf16x8*)(wsm + SWZ(c, ks * 64 + lk * 16));
            acc[nt] = __builtin_amdgcn_mfma_f32_16x16x32_bf16(afr[ks], bfr, acc[nt], 0, 0, 0);
        }
    }
    __syncthreads();   // all waves done reading xs -> reuse as output tile

    #pragma unroll
    for (int nt = 0; nt < 8; nt++) {
        int c = nt * 16 + lm;
        #pragma unroll
        for (int e = 0; e < 4; e++) {
            int row = r0 + lk * 4 + e;
            *(unsigned short*)(xs + SWZ(row, c * 2)) = bf16r(acc[nt][e]);
        }
    }
    __syncthreads();

    #pragma unroll
    for (int it = 0; it < 4; it++) {
        int idx = it * 256 + tid;
        int row = idx >> 4, q = idx & 15;
        if (row0 + row < N) {
            uint4 v = *(const uint4*)(xs + SWZ(row, q * 16));
            h1b[(size_t)(row0 + row) * 16 + q] = v;
        }
    }
    {
        int row = tid >> 2, h = tid & 3;
        if (row0 + row < N) {
            float sd = 0.f, dd = 0.f;
            #pragma unroll
            for (int q = 0; q < 4; q++) {
                uint4 v = *(const uint4*)(xs + SWZ(row, h * 64 + q * 16));
                unsigned uu[4] = {v.x, v.y, v.z, v.w};
                #pragma unroll
                for (int j = 0; j < 4; j++) {
                    int k = h * 32 + q * 8 + 2 * j;
                    sd = fmaf(bf_lo(uu[j]), a_s[k], sd);
                    sd = fmaf(bf_hi(uu[j]), a_s[k + 1], sd);
                    dd = fmaf(bf_lo(uu[j]), a_d[k], dd);
                    dd = fmaf(bf_hi(uu[j]), a_d[k + 1], dd);
                }
            }
            as1[(row0 + row) * 4 + h] = sd;
            ad1[(row0 + row) * 4 + h] = dd;
        }
    }
}

// ---------------- Layer 1 aggregation: 2 edges/wave, 32 lanes x 4ch, 16 in flight -------

#define A1SLOT(u, ex)                                              \
    {                                                              \
        den += ex;                                                 \
        a0 = fmaf(ex, bf_lo(u.x), a0);                             \
        a1 = fmaf(ex, bf_hi(u.x), a1);                             \
        a2 = fmaf(ex, bf_lo(u.y), a2);                             \
        a3 = fmaf(ex, bf_hi(u.y), a3);                             \
    }

__global__ __launch_bounds__(256) void agg1_kernel(const int* __restrict__ rowptr,
                                                   const int* __restrict__ col,
                                                   const uint2* __restrict__ h1v,
                                                   const float* __restrict__ exa,
                                                   const float* __restrict__ b1,
                                                   uint2* __restrict__ out1v, int N) {
    int lane = threadIdx.x & 63;
    int wid = __builtin_amdgcn_readfirstlane(threadIdx.x >> 6);
    int n = blockIdx.x * 4 + wid;
    if (n >= N) return;
    int half = lane >> 5;                // which edge of a pair
    int cl = lane & 31;                  // channel quad: channels 4*cl .. 4*cl+3
    int hh = cl >> 3;                    // head
    int beg = rowptr[n], end = rowptr[n + 1];
    float a0 = 0.f, a1 = 0.f, a2 = 0.f, a3 = 0.f, den = 0.f;
    int i = beg;
    for (; i + 16 <= end; i += 16) {
        int e0 = i + half,      e1 = i + 2 + half,  e2 = i + 4 + half,  e3 = i + 6 + half;
        int e4 = i + 8 + half,  e5 = i + 10 + half, e6 = i + 12 + half, e7 = i + 14 + half;
        int s0 = col[e0], s1 = col[e1], s2 = col[e2], s3 = col[e3];
        int s4 = col[e4], s5 = col[e5], s6 = col[e6], s7 = col[e7];
        uint2 u0 = h1v[s0 * 32 + cl], u1 = h1v[s1 * 32 + cl];
        uint2 u2 = h1v[s2 * 32 + cl], u3 = h1v[s3 * 32 + cl];
        uint2 u4 = h1v[s4 * 32 + cl], u5 = h1v[s5 * 32 + cl];
        uint2 u6 = h1v[s6 * 32 + cl], u7 = h1v[s7 * 32 + cl];
        float x0 = exa[e0 * 4 + hh], x1 = exa[e1 * 4 + hh];
        float x2 = exa[e2 * 4 + hh], x3 = exa[e3 * 4 + hh];
        float x4 = exa[e4 * 4 + hh], x5 = exa[e5 * 4 + hh];
        float x6 = exa[e6 * 4 + hh], x7 = exa[e7 * 4 + hh];
        A1SLOT(u0, x0) A1SLOT(u1, x1) A1SLOT(u2, x2) A1SLOT(u3, x3)
        A1SLOT(u4, x4) A1SLOT(u5, x5) A1SLOT(u6, x6) A1SLOT(u7, x7)
    }
    for (; i + 2 <= end; i += 2) {
        int e = i + half;
        int s = col[e];
        uint2 u = h1v[s * 32 + cl];
        float x = exa[e * 4 + hh];
        A1SLOT(u, x)
    }
    if (i < end && half == 0) {
        int s = col[i];
        uint2 u = h1v[s * 32 + cl];
        float x = exa[i * 4 + hh];
        A1SLOT(u, x)
    }
    den += __shfl_xor(den, 32, 64);
    a0 += __shfl_xor(a0, 32, 64);
    a1 += __shfl_xor(a1, 32, 64);
    a2 += __shfl_xor(a2, 32, 64);
    a3 += __shfl_xor(a3, 32, 64);
    if (half == 0) {
        float4 bb = ((const float4*)b1)[cl];
        float o0 = fmaxf(a0 / den + bb.x, 0.f);
        float o1 = fmaxf(a1 / den + bb.y, 0.f);
        float o2 = fmaxf(a2 / den + bb.z, 0.f);
        float o3 = fmaxf(a3 / den + bb.w, 0.f);
        uint2 pk;
        pk.x = pack_bf16x2(o0, o1);
        pk.y = pack_bf16x2(o2, o3);
        out1v[n * 32 + cl] = pk;
    }
}

// ================= Layer 2 GEMM (MFMA bf16): h2 = relu_h @ W2, plus as2/ad2 =============

__global__ __launch_bounds__(256) void gemm2_kernel(const uint4* __restrict__ out1b,
                                                    const unsigned short* __restrict__ W2T,
                                                    const float* __restrict__ a_s,
                                                    const float* __restrict__ a_d,
                                                    uint4* __restrict__ h2b,
                                                    float* __restrict__ as2,
                                                    float* __restrict__ ad2, int N) {
    __shared__ char xs[16384];          // A tile / later h2 tile
    __shared__ char wsm[8192];          // W2T 32x128 bf16
    int tid = threadIdx.x;
    int row0 = blockIdx.x * 64;

    #pragma unroll
    for (int it = 0; it < 2; it++) {
        int idx = it * 256 + tid;
        int n = idx >> 4, kq = idx & 15;
        uint4 v = ((const uint4*)W2T)[idx];
        *(uint4*)(wsm + SWZ(n, kq * 16)) = v;
    }
    #pragma unroll
    for (int it = 0; it < 4; it++) {
        int idx = it * 256 + tid;
        int r = idx >> 4, q = idx & 15;
        int row = row0 + r;
        uint4 v = (row < N) ? out1b[(size_t)row * 16 + q] : make_uint4(0, 0, 0, 0);
        *(uint4*)(xs + SWZ(r, q * 16)) = v;
    }
    __syncthreads();

    int wv = tid >> 6, lane = tid & 63;
    int r0 = wv * 16;
    int lm = lane & 15, lk = lane >> 4;

    bf16x8 afr[4];
    #pragma unroll
    for (int ks = 0; ks < 4; ks++) {
        int row = r0 + lm;
        afr[ks] = *(const bf16x8*)(xs + SWZ(row, ks * 64 + lk * 16));
    }
    f32x4 acc[2];
    acc[0] = (f32x4){0.f, 0.f, 0.f, 0.f};
    acc[1] = (f32x4){0.f, 0.f, 0.f, 0.f};
    #pragma unroll
    for (int nt = 0; nt < 2; nt++) {
        int c = nt * 16 + lm;
        #pragma unroll
        for (int ks = 0; ks < 4; ks++) {
            bf16x8 bfr = *(const bf16x8*)(wsm + SWZ(c, ks * 64 + lk * 16));
            acc[nt] = __builtin_amdgcn_mfma_f32_16x16x32_bf16(afr[ks], bfr, acc[nt], 0, 0, 0);
        }
    }
    __syncthreads();

    #pragma unroll
    for (int nt = 0; nt < 2; nt++) {
        int c = nt * 16 + lm;
        #pragma unroll
        for (int e = 0; e < 4; e++) {
            int row = r0 + lk * 4 + e;
            *(unsigned short*)(xs + SWZ(row, c * 2)) = bf16r(acc[nt][e]);
        }
    }
    __syncthreads();

    {
        int row = tid >> 2, q = tid & 3;
        if (row0 + row < N) {
            uint4 v = *(const uint4*)(xs + SWZ(row, q * 16));
            h2b[(size_t)(row0 + row) * 4 + q] = v;
        }
    }
    if (tid < 64 && row0 + tid < N) {
        float sd = 0.f, dd = 0.f;
        #pragma unroll
        for (int q = 0; q < 4; q++) {
            uint4 v = *(const uint4*)(xs + SWZ(tid, q * 16));
            unsigned uu[4] = {v.x, v.y, v.z, v.w};
            #pragma unroll
            for (int j = 0; j < 4; j++) {
                int k = q * 8 + 2 * j;
                sd = fmaf(bf_lo(uu[j]), a_s[k], sd);
                sd = fmaf(bf_hi(uu[j]), a_s[k + 1], sd);
                dd = fmaf(bf_lo(uu[j]), a_d[k], dd);
                dd = fmaf(bf_hi(uu[j]), a_d[k + 1], dd);
            }
        }
        as2[row0 + tid] = sd;
        ad2[row0 + tid] = dd;
    }
}

// ---------------- Layer 2 aggregation: 8 edges/wave, 8 lanes x 4ch, 16 in flight --------

#define A2SLOT(u, l)                                               \
    {                                                              \
        float e = l + adn;                                         \
        e = fmaxf(e, e * NEG_SLOPE);                               \
        float ex = __expf(e);                                      \
        den += ex;                                                 \
        a0 = fmaf(ex, bf_lo(u.x), a0);                             \
        a1 = fmaf(ex, bf_hi(u.x), a1);                             \
        a2 = fmaf(ex, bf_lo(u.y), a2);                             \
        a3 = fmaf(ex, bf_hi(u.y), a3);                             \
    }

__global__ __launch_bounds__(256) void agg2_kernel(const int* __restrict__ rowptr,
                                                   const int* __restrict__ col,
                                                   const uint2* __restrict__ h2v,
                                                   const float* __restrict__ as2,
                                                   const float* __restrict__ ad2,
                                                   const float* __restrict__ b2,
                                                   float* __restrict__ out, int N) {
    int lane = threadIdx.x & 63;
    int wid = __builtin_amdgcn_readfirstlane(threadIdx.x >> 6);
    int n = blockIdx.x * 4 + wid;
    if (n >= N) return;
    int q8 = lane >> 3;                  // edge slot 0..7
    int cl = lane & 7;                   // channel quad: channels 4*cl .. 4*cl+3
    float adn = ad2[n];
    int beg = rowptr[n], end = rowptr[n + 1];
    float a0 = 0.f, a1 = 0.f, a2 = 0.f, a3 = 0.f, den = 0.f;
    int i = beg;
    for (; i + 16 <= end; i += 16) {
        int e0 = i + q8, e1 = i + 8 + q8;
        int s0 = col[e0], s1 = col[e1];
        uint2 u0 = h2v[s0 * 8 + cl];
        uint2 u1 = h2v[s1 * 8 + cl];
        float l0 = as2[s0], l1 = as2[s1];
        A2SLOT(u0, l0) A2SLOT(u1, l1)
    }
    for (; i < end; i += 8) {
        int e = i + q8;
        if (e < end) {
            int s = col[e];
            uint2 u = h2v[s * 8 + cl];
            float l = as2[s];
            A2SLOT(u, l)
        }
    }
    den += __shfl_xor(den, 8, 64);
    den += __shfl_xor(den, 16, 64);
    den += __shfl_xor(den, 32, 64);
    a0 += __shfl_xor(a0, 8, 64);  a0 += __shfl_xor(a0, 16, 64);  a0 += __shfl_xor(a0, 32, 64);
    a1 += __shfl_xor(a1, 8, 64);  a1 += __shfl_xor(a1, 16, 64);  a1 += __shfl_xor(a1, 32, 64);
    a2 += __shfl_xor(a2, 8, 64);  a2 += __shfl_xor(a2, 16, 64);  a2 += __shfl_xor(a2, 32, 64);
    a3 += __shfl_xor(a3, 8, 64);  a3 += __shfl_xor(a3, 16, 64);  a3 += __shfl_xor(a3, 32, 64);
    if (q8 == 0) {
        float4 bb = ((const float4*)b2)[cl];
        float4 o;
        o.x = a0 / den + bb.x;
        o.y = a1 / den + bb.y;
        o.z = a2 / den + bb.z;
        o.w = a3 / den + bb.w;
        ((float4*)out)[n * 8 + cl] = o;
    }
}

// ---------------- launch ----------------

extern "C" void kernel_launch(void* const* d_in, const int* in_sizes, int n_in,
                              void* d_out, int out_size, void* d_ws, size_t ws_size,
                              hipStream_t stream) {
    const float* x    = (const float*)d_in[0];
    const int*   ei   = (const int*)d_in[1];
    const float* W1   = (const float*)d_in[2];
    const float* a_s1 = (const float*)d_in[3];
    const float* a_d1 = (const float*)d_in[4];
    const float* b1   = (const float*)d_in[5];
    const float* W2   = (const float*)d_in[6];
    const float* a_s2 = (const float*)d_in[7];
    const float* a_d2 = (const float*)d_in[8];
    const float* b2   = (const float*)d_in[9];

    int N = in_sizes[0] / 128;
    int E = in_sizes[1] / 2;
    const int* srcA = ei;
    const int* dstA = ei + E;
    int Etot = E + N;

    char* ws = (char*)d_ws;
    size_t off = 0;
    auto alloc = [&](size_t bytes) {
        void* p = ws + off;
        off += (bytes + 255) & ~(size_t)255;
        return p;
    };
    unsigned* h1b   = (unsigned*)alloc((size_t)N * 128 * 2);
    unsigned* out1b = (unsigned*)alloc((size_t)N * 128 * 2);
    unsigned* h2b   = (unsigned*)alloc((size_t)N * 32 * 2);
    float* as1      = (float*)alloc((size_t)N * 4 * 4);
    float* ad1      = (float*)alloc((size_t)N * 4 * 4);
    float* as2      = (float*)alloc((size_t)N * 4);
    float* ad2      = (float*)alloc((size_t)N * 4);
    int*   rowptr   = (int*)alloc((size_t)(N + 1) * 4);
    int*   col      = (int*)alloc((size_t)Etot * 4);
    int*   edst     = (int*)alloc((size_t)Etot * 4);
    unsigned* pairs = (unsigned*)alloc((size_t)Etot * 4);
    float* exa      = (float*)alloc((size_t)Etot * 16);
    unsigned short* W1T = (unsigned short*)alloc(128 * 128 * 2);
    unsigned short* W2T = (unsigned short*)alloc(32 * 128 * 2);

    int nbuckets = (N + 255) >> 8;                 // 391
    int nblk1 = (Etot + EPB - 1) / EPB;            // 208
    int M = nbuckets * nblk1;
    int*   partial = (int*)alloc((size_t)M * 4);
    int nbs = (M + 255) / 256;
    int*   psum    = (int*)alloc((size_t)1024 * 4);

    // weight transpose/convert + layer-1 GEMM (as1/ad1 needed by exk)
    hipLaunchKernelGGL(wcvt_kernel, dim3(64), dim3(256), 0, stream, W1, W1T, 128, 16384);
    hipLaunchKernelGGL(wcvt_kernel, dim3(16), dim3(256), 0, stream, W2, W2T, 32, 4096);
    hipLaunchKernelGGL(gemm1_kernel, dim3((N + 63) / 64), dim3(256), 0, stream,
                       x, W1T, a_s1, a_d1, (uint4*)h1b, as1, ad1, N);

    // CSR build (LDS-atomic two-level counting sort)
    hipLaunchKernelGGL(p1_hist, dim3(nblk1), dim3(256), 0, stream,
                       dstA, E, N, nblk1, nbuckets, partial);
    hipLaunchKernelGGL(gscan_bsum, dim3(nbs), dim3(256), 0, stream, partial, psum, M);
    hipLaunchKernelGGL(gscan_psum, dim3(1), dim3(1024), 0, stream, psum, nbs);
    hipLaunchKernelGGL(gscan_final, dim3(nbs), dim3(256), 0, stream, partial, psum, M);
    hipLaunchKernelGGL(p1_scatter, dim3(nblk1), dim3(256), 0, stream,
                       srcA, dstA, E, N, nblk1, nbuckets, partial, pairs);
    hipLaunchKernelGGL(p2_kernel, dim3(nbuckets), dim3(256), 0, stream,
                       pairs, partial, nblk1, nbuckets, Etot, N, rowptr, col, edst);

    // per-edge attention numerators (fully parallel)
    hipLaunchKernelGGL(exk_kernel, dim3((Etot + 255) / 256), dim3(256), 0, stream,
                       col, edst, (const float4*)as1, (const float4*)ad1, (float4*)exa, Etot);

    // GAT layers
    hipLaunchKernelGGL(agg1_kernel, dim3((N + 3) / 4), dim3(256), 0, stream,
                       rowptr, col, (const uint2*)h1b, exa, b1, (uint2*)out1b, N);
    hipLaunchKernelGGL(gemm2_kernel, dim3((N + 63) / 64), dim3(256), 0, stream,
                       (const uint4*)out1b, W2T, a_s2, a_d2, (uint4*)h2b, as2, ad2, N);
    hipLaunchKernelGGL(agg2_kernel, dim3((N + 3) / 4), dim3(256), 0, stream,
                       rowptr, col, (const uint2*)h2b, as2, ad2, b2, (float*)d_out, N);
}